// Round 8
// baseline (609.327 us; speedup 1.0000x reference)
//
#include <hip/hip_runtime.h>

typedef unsigned short u16;
typedef unsigned int   u32;

typedef __bf16 bf16x8 __attribute__((ext_vector_type(8)));
typedef float  f32x4  __attribute__((ext_vector_type(4)));

__device__ __forceinline__ float bf2f(u16 u) {
  u32 x = ((u32)u) << 16; float f; __builtin_memcpy(&f, &x, 4); return f;
}
__device__ __forceinline__ u16 f2bf(float f) {
  u32 x; __builtin_memcpy(&x, &f, 4);
  x += 0x7fffu + ((x >> 16) & 1u);
  return (u16)(x >> 16);
}
__device__ __forceinline__ void gl2lds16(const void* g, void* l) {
  __builtin_amdgcn_global_load_lds((const __attribute__((address_space(1))) void*)g,
                                   (__attribute__((address_space(3))) void*)l, 16, 0, 0);
}

// ---------------- K1: hT = relu(X @ W1 + b1)^T, hT:[64][8192] f32 (transposed) ----------------
// Transposed store: each of the 64 per-thread outputs is a lane-coalesced wave store, and
// downstream consumers (k_bn column reduce, k_dyqk j-loop) read fully coalesced.
__global__ __launch_bounds__(256) void k_h(const float* __restrict__ hd, const float* __restrict__ W1,
                                           const float* __restrict__ b1, float* __restrict__ hT)
{
  __shared__ float w1s[12 * 64];
  __shared__ float b1s[64];
  int t = threadIdx.x;
  for (int idx = t; idx < 768; idx += 256) w1s[idx] = W1[idx];
  if (t < 64) b1s[t] = b1[t];
  __syncthreads();
  int i = blockIdx.x * 256 + t;
  int b = i >> 10, n = i & 1023;
  float x[12];
#pragma unroll
  for (int l = 0; l < 12; ++l) x[l] = hd[(b * 12 + l) * 1024 + n];
  float acc[64];
#pragma unroll
  for (int j = 0; j < 64; ++j) acc[j] = b1s[j];
#pragma unroll
  for (int l = 0; l < 12; ++l) {
    float xl = x[l];
#pragma unroll
    for (int j = 0; j < 64; ++j) acc[j] += xl * w1s[l * 64 + j];
  }
#pragma unroll
  for (int j = 0; j < 64; ++j) hT[(size_t)j * 8192 + i] = fmaxf(acc[j], 0.f);
}

// ---------------- K2: BN stats + finalize fused; block j owns column j ----------------
__global__ __launch_bounds__(256) void k_bn(const float* __restrict__ hT, const float* __restrict__ gamma,
                                            const float* __restrict__ beta, float* __restrict__ ss)
{
  int j = blockIdx.x;  // 64 blocks
  int t = threadIdx.x;
  const float* row = hT + (size_t)j * 8192;
  float s = 0.f, q = 0.f;
  for (int it = 0; it < 32; ++it) {
    float v = row[it * 256 + t];
    s += v; q += v * v;
  }
  __shared__ float ls[256], lq[256];
  ls[t] = s; lq[t] = q;
  __syncthreads();
  for (int off = 128; off > 0; off >>= 1) {
    if (t < off) { ls[t] += ls[t + off]; lq[t] += lq[t + off]; }
    __syncthreads();
  }
  if (t == 0) {
    float mu = ls[0] * (1.f / 8192.f);
    float var = lq[0] * (1.f / 8192.f) - mu * mu;
    float inv = rsqrtf(var + 1e-5f);
    float sc = gamma[j] * inv;
    ss[j] = sc;
    ss[64 + j] = beta[j] - mu * sc;
  }
}

// ---------------- K3: dy_feat + Q/K (emb part fused inline); Q f32 transposed, K bf16 transposed --
__global__ __launch_bounds__(256) void k_dyqk(const float* __restrict__ hT, const float* __restrict__ ss,
                                              const float* __restrict__ W2, const float* __restrict__ b2,
                                              const float* __restrict__ WQ, const float* __restrict__ WK,
                                              const float* __restrict__ embd, const float* __restrict__ embu,
                                              float* __restrict__ QTf, u16* __restrict__ KTb)
{
  __shared__ float w2s[64 * 32], wqs[32 * 32], wks[32 * 32];
  __shared__ float wqe[16 * 32], wke[16 * 32];  // WQ/WK rows 32..47 (embedding part)
  __shared__ float b2s[32], scs[64], shs[64];
  int t = threadIdx.x;
  for (int idx = t; idx < 2048; idx += 256) w2s[idx] = W2[idx];
  for (int idx = t; idx < 1024; idx += 256) { wqs[idx] = WQ[idx]; wks[idx] = WK[idx]; }
  for (int idx = t; idx < 512; idx += 256) { wqe[idx] = WQ[1024 + idx]; wke[idx] = WK[1024 + idx]; }
  if (t < 32) b2s[t] = b2[t];
  if (t < 64) { scs[t] = ss[t]; shs[t] = ss[64 + t]; }
  __syncthreads();
  int i = blockIdx.x * 256 + t;
  int b = i >> 10, n = i & 1023;
  float dy[32];
#pragma unroll
  for (int o = 0; o < 32; ++o) dy[o] = b2s[o];
  for (int j = 0; j < 64; ++j) {
    float hj = hT[(size_t)j * 8192 + i] * scs[j] + shs[j];  // coalesced over i
#pragma unroll
    for (int o = 0; o < 32; ++o) dy[o] += hj * w2s[j * 32 + o];
  }
  float tq[32], tk[32];
#pragma unroll
  for (int o = 0; o < 32; ++o) { tq[o] = 0.f; tk[o] = 0.f; }
  for (int j = 0; j < 32; ++j) {
    float d = dy[j];
#pragma unroll
    for (int o = 0; o < 32; ++o) { tq[o] += d * wqs[j * 32 + o]; tk[o] += d * wks[j * 32 + o]; }
  }
#pragma unroll
  for (int e = 0; e < 2; ++e) {
    const float* emb = e ? embu : embd;
    float em[16];
#pragma unroll
    for (int d = 0; d < 16; ++d) em[d] = emb[n * 16 + d];
    size_t qb = ((size_t)(e * 8 + b) * 32) * 1024 + n;
#pragma unroll
    for (int o = 0; o < 32; ++o) {
      float eq = 0.f, ek = 0.f;
#pragma unroll
      for (int d = 0; d < 16; ++d) { eq += em[d] * wqe[d * 32 + o]; ek += em[d] * wke[d * 32 + o]; }
      QTf[qb + (size_t)o * 1024] = tq[o] + eq;          // coalesced over n
      KTb[qb + (size_t)o * 1024] = f2bf(tk[o] + ek);
    }
  }
}

// ---------------- K5: fused logits/exp/mask/row-normalize + order-1 output + G ----------------
// softmax denominator cancels against row normalization; logits are O(1) so no max-subtraction.
__global__ __launch_bounds__(256) void k_attn(const float* __restrict__ QTf, const u16* __restrict__ KTb,
                                              const float* __restrict__ adj0, const float* __restrict__ adj1,
                                              u16* __restrict__ G, float* __restrict__ out)
{
  int blk = (blockIdx.x & 7) * 64 + (blockIdx.x >> 3);  // T1 chunked swizzle, 512 wgs
  int rg = blk & 31, b = (blk >> 5) & 7, e = blk >> 8;
  int t = threadIdx.x;
  int eb = e * 8 + b;
  int wv = t >> 6, lane = t & 63;
  const float* adj = e ? adj1 : adj0;
  const u16* Kp = KTb + ((size_t)eb << 15);      // [h][m] bf16 slab, 64 KB, L2-resident
  const float* Qp = QTf + ((size_t)eb << 15);
  u16* Gp = G + ((size_t)eb << 20);
  float* o1 = out + (((size_t)(2 * e) * 8 + b) << 21);
  const float sc = 0.17677669529663687f;  // 1/sqrt(32)
#pragma unroll
  for (int grp = 0; grp < 2; ++grp) {
    int r0 = rg * 32 + wv * 8 + grp * 4;  // 4 rows per group
    float accA[4][8], accB[4][8];
#pragma unroll
    for (int r = 0; r < 4; ++r)
#pragma unroll
      for (int k = 0; k < 8; ++k) { accA[r][k] = 0.f; accB[r][k] = 0.f; }
    for (int hh = 0; hh < 32; ++hh) {
      float4 qv = *(const float4*)(Qp + hh * 1024 + r0);
      uint4 ka = *(const uint4*)(Kp + hh * 1024 + lane * 8);        // m = lane*8 .. +7
      uint4 kb = *(const uint4*)(Kp + hh * 1024 + 512 + lane * 8);  // m = 512 + lane*8 .. +7
      float kf[8] = {bf2f((u16)ka.x), bf2f((u16)(ka.x >> 16)), bf2f((u16)ka.y), bf2f((u16)(ka.y >> 16)),
                     bf2f((u16)ka.z), bf2f((u16)(ka.z >> 16)), bf2f((u16)ka.w), bf2f((u16)(ka.w >> 16))};
      float kg[8] = {bf2f((u16)kb.x), bf2f((u16)(kb.x >> 16)), bf2f((u16)kb.y), bf2f((u16)(kb.y >> 16)),
                     bf2f((u16)kb.z), bf2f((u16)(kb.z >> 16)), bf2f((u16)kb.w), bf2f((u16)(kb.w >> 16))};
#pragma unroll
      for (int k = 0; k < 8; ++k) {
        accA[0][k] += qv.x * kf[k]; accA[1][k] += qv.y * kf[k];
        accA[2][k] += qv.z * kf[k]; accA[3][k] += qv.w * kf[k];
        accB[0][k] += qv.x * kg[k]; accB[1][k] += qv.y * kg[k];
        accB[2][k] += qv.z * kg[k]; accB[3][k] += qv.w * kg[k];
      }
    }
#pragma unroll
    for (int r = 0; r < 4; ++r) {
      int gr = r0 + r;
      const float* arow = adj + ((size_t)gr << 10);
      int mA = lane * 8, mB = 512 + lane * 8;
      float4 a0 = *(const float4*)(arow + mA);
      float4 a1 = *(const float4*)(arow + mA + 4);
      float4 c0 = *(const float4*)(arow + mB);
      float4 c1 = *(const float4*)(arow + mB + 4);
      float af[8] = {a0.x, a0.y, a0.z, a0.w, a1.x, a1.y, a1.z, a1.w};
      float bfv[8] = {c0.x, c0.y, c0.z, c0.w, c1.x, c1.y, c1.z, c1.w};
      float ta[8], tb[8];
      float p = 0.f;
#pragma unroll
      for (int k = 0; k < 8; ++k) { ta[k] = (af[k] + 1e-7f) * __expf(accA[r][k] * sc); p += ta[k]; }
#pragma unroll
      for (int k = 0; k < 8; ++k) { tb[k] = (bfv[k] + 1e-7f) * __expf(accB[r][k] * sc); p += tb[k]; }
#pragma unroll
      for (int off = 32; off > 0; off >>= 1) p += __shfl_xor(p, off);
      float inv = 1.f / p;
      if (!__builtin_isfinite(inv)) inv = 0.f;
      float ga[8], gb[8];
#pragma unroll
      for (int k = 0; k < 8; ++k) { ga[k] = ta[k] * inv; gb[k] = tb[k] * inv; }
      // G row with diagonal intact (needed for g@g), bf16
      uint4 pa, pb;
      pa.x = f2bf(ga[0]) | ((u32)f2bf(ga[1]) << 16);  pa.y = f2bf(ga[2]) | ((u32)f2bf(ga[3]) << 16);
      pa.z = f2bf(ga[4]) | ((u32)f2bf(ga[5]) << 16);  pa.w = f2bf(ga[6]) | ((u32)f2bf(ga[7]) << 16);
      pb.x = f2bf(gb[0]) | ((u32)f2bf(gb[1]) << 16);  pb.y = f2bf(gb[2]) | ((u32)f2bf(gb[3]) << 16);
      pb.z = f2bf(gb[4]) | ((u32)f2bf(gb[5]) << 16);  pb.w = f2bf(gb[6]) | ((u32)f2bf(gb[7]) << 16);
      *(uint4*)(Gp + ((size_t)gr << 10) + mA) = pa;
      *(uint4*)(Gp + ((size_t)gr << 10) + mB) = pb;
      // order-1 output: zero diag, row duplicated, f32
#pragma unroll
      for (int k = 0; k < 8; ++k) {
        if (mA + k == gr) ga[k] = 0.f;
        if (mB + k == gr) gb[k] = 0.f;
      }
      size_t ob = (size_t)gr << 11;
      float4 fa0 = {ga[0], ga[1], ga[2], ga[3]}, fa1 = {ga[4], ga[5], ga[6], ga[7]};
      float4 fb0 = {gb[0], gb[1], gb[2], gb[3]}, fb1 = {gb[4], gb[5], gb[6], gb[7]};
      *(float4*)(o1 + ob + mA) = fa0;         *(float4*)(o1 + ob + mA + 4) = fa1;
      *(float4*)(o1 + ob + mB) = fb0;         *(float4*)(o1 + ob + mB + 4) = fb1;
      *(float4*)(o1 + ob + 1024 + mA) = fa0;  *(float4*)(o1 + ob + 1024 + mA + 4) = fa1;
      *(float4*)(o1 + ob + 1024 + mB) = fb0;  *(float4*)(o1 + ob + 1024 + mB + 4) = fb1;
    }
  }
}

// ---------------- K5t: G -> Gt (64x64 LDS tile transpose, pad 66 to dodge bank conflicts) -----
__global__ __launch_bounds__(256) void k_tr(const u16* __restrict__ G, u16* __restrict__ Gt)
{
  __shared__ u16 tile[64 * 66];
  int blk = blockIdx.x;
  int mat = blk >> 8, tl = blk & 255, ti = tl >> 4, tj = tl & 15;
  size_t mo = (size_t)mat << 20;
  int t = threadIdx.x;
#pragma unroll
  for (int half = 0; half < 2; ++half) {
    int idx = t + half * 256;
    int row = idx >> 3, q = idx & 7;
    uint4 v = *(const uint4*)(G + mo + (size_t)(ti * 64 + row) * 1024 + tj * 64 + q * 8);
    u16* d = &tile[row * 66 + q * 8];
    d[0] = (u16)v.x; d[1] = (u16)(v.x >> 16);
    d[2] = (u16)v.y; d[3] = (u16)(v.y >> 16);
    d[4] = (u16)v.z; d[5] = (u16)(v.z >> 16);
    d[6] = (u16)v.w; d[7] = (u16)(v.w >> 16);
  }
  __syncthreads();
#pragma unroll
  for (int half = 0; half < 2; ++half) {
    int idx = t + half * 256;
    int row = idx >> 3, q = idx & 7;
    u16 s0 = tile[(q * 8 + 0) * 66 + row], s1 = tile[(q * 8 + 1) * 66 + row];
    u16 s2 = tile[(q * 8 + 2) * 66 + row], s3 = tile[(q * 8 + 3) * 66 + row];
    u16 s4 = tile[(q * 8 + 4) * 66 + row], s5 = tile[(q * 8 + 5) * 66 + row];
    u16 s6 = tile[(q * 8 + 6) * 66 + row], s7 = tile[(q * 8 + 7) * 66 + row];
    uint4 v;
    v.x = s0 | ((u32)s1 << 16); v.y = s2 | ((u32)s3 << 16);
    v.z = s4 | ((u32)s5 << 16); v.w = s6 | ((u32)s7 << 16);
    *(uint4*)(Gt + mo + (size_t)(tj * 64 + row) * 1024 + ti * 64 + q * 8) = v;
  }
}

// ---------------- K6: batched C = G@G via bf16 MFMA; order-2 output fused in epilogue --------
// 2-phase double-buffered staging (R6 measured-best form): prefetch next K-tile before compute,
// one __syncthreads per K-step.
__global__ __launch_bounds__(256) void k_gemm(const u16* __restrict__ G, const u16* __restrict__ Gt,
                                              float* __restrict__ out)
{
  __shared__ __align__(16) u16 As[2][128 * 32];
  __shared__ __align__(16) u16 Bs[2][128 * 32];
  int bid = (blockIdx.x & 7) * 128 + (blockIdx.x >> 3);  // T1 chunked swizzle, 1024 wgs
  int mat = bid >> 6, tile = bid & 63, ti = tile >> 3, tj = tile & 7;
  size_t mo = (size_t)mat << 20;
  const u16* A = G + mo;
  const u16* Bm = Gt + mo;  // Bt[n][k] = G[k][n]
  int t = threadIdx.x;
  int w = t >> 6, lane = t & 63;
  int quad = lane >> 4, l16 = lane & 15;
  int wr = (w & 1) * 64, wc = (w >> 1) * 64;
  f32x4 acc[4][4];
#pragma unroll
  for (int i = 0; i < 4; ++i)
#pragma unroll
    for (int j = 0; j < 4; ++j) acc[i][j] = f32x4{0.f, 0.f, 0.f, 0.f};

#define STAGE(buf, kk)                                                                  \
  {                                                                                     \
    _Pragma("unroll")                                                                   \
    for (int it = 0; it < 2; ++it) {                                                    \
      int sbase = (it * 4 + w) * 64;                                                    \
      int r = (sbase + lane) >> 2, c = (sbase + lane) & 3;                              \
      gl2lds16(A + (size_t)(ti * 128 + r) * 1024 + (kk) + c * 8,                        \
               (u16*)As[buf] + (size_t)sbase * 8);                                      \
      gl2lds16(Bm + (size_t)(tj * 128 + r) * 1024 + (kk) + c * 8,                       \
               (u16*)Bs[buf] + (size_t)sbase * 8);                                      \
    }                                                                                   \
  }

  STAGE(0, 0);
  __syncthreads();
  int cur = 0;
  for (int k0 = 0; k0 < 1024; k0 += 32) {
    if (k0 + 32 < 1024) STAGE(cur ^ 1, k0 + 32);   // prefetch overlaps compute below
    bf16x8 af[4], bfr[4];
#pragma unroll
    for (int mt = 0; mt < 4; ++mt)
      af[mt] = *(const bf16x8*)&As[cur][(wr + mt * 16 + l16) * 32 + quad * 8];
#pragma unroll
    for (int nt = 0; nt < 4; ++nt)
      bfr[nt] = *(const bf16x8*)&Bs[cur][(wc + nt * 16 + l16) * 32 + quad * 8];
#pragma unroll
    for (int mt = 0; mt < 4; ++mt)
#pragma unroll
      for (int nt = 0; nt < 4; ++nt)
        acc[mt][nt] = __builtin_amdgcn_mfma_f32_16x16x32_bf16(af[mt], bfr[nt], acc[mt][nt], 0, 0, 0);
    __syncthreads();  // drains vmcnt (prefetch done) + lgkmcnt (ds_reads done) for all waves
    cur ^= 1;
  }
#undef STAGE
  int e = mat >> 3, bb = mat & 7;
  float* o2 = out + (((size_t)(2 * e + 1) * 8 + bb) << 21);
#pragma unroll
  for (int mt = 0; mt < 4; ++mt)
#pragma unroll
    for (int r = 0; r < 4; ++r) {
      int gr = ti * 128 + wr + mt * 16 + quad * 4 + r;
      size_t rb = (size_t)gr << 11;
#pragma unroll
      for (int nt = 0; nt < 4; ++nt) {
        int gc = tj * 128 + wc + nt * 16 + l16;
        float v = (gr == gc) ? 0.f : acc[mt][nt][r];
        o2[rb + gc] = v;
        o2[rb + 1024 + gc] = v;
      }
    }
}

extern "C" void kernel_launch(void* const* d_in, const int* in_sizes, int n_in,
                              void* d_out, int out_size, void* d_ws, size_t ws_size,
                              hipStream_t stream) {
  const float* hd    = (const float*)d_in[0];
  const float* embd  = (const float*)d_in[1];
  const float* embu  = (const float*)d_in[2];
  const float* adj0  = (const float*)d_in[3];
  const float* adj1  = (const float*)d_in[4];
  const float* W1    = (const float*)d_in[5];
  const float* b1    = (const float*)d_in[6];
  const float* gamma = (const float*)d_in[7];
  const float* beta  = (const float*)d_in[8];
  const float* W2    = (const float*)d_in[9];
  const float* b2    = (const float*)d_in[10];
  const float* WQ    = (const float*)d_in[11];
  const float* WK    = (const float*)d_in[12];
  char* ws = (char*)d_ws;
  float* ss      = (float*)(ws + 1024);      // 128 f32 (scale, shift)
  float* hT      = (float*)(ws + 528384);    // [64][8192] f32 transposed  (2 MB)
  float* QTf     = (float*)(ws + 2625536);   // [16][32][1024] f32         (2 MB)
  u16* KTb       = (u16*)(ws + 4722688);     // [16][32][1024] bf16        (1 MB)
  u16* G         = (u16*)(ws + 5771264);     // [16][1024][1024] bf16      (32 MB)
  u16* Gt        = (u16*)(ws + 39325696);    // transpose                  (32 MB)
  float* out     = (float*)d_out;

  k_h<<<32, 256, 0, stream>>>(hd, W1, b1, hT);
  k_bn<<<64, 256, 0, stream>>>(hT, gamma, beta, ss);
  k_dyqk<<<32, 256, 0, stream>>>(hT, ss, W2, b2, WQ, WK, embd, embu, QTf, KTb);
  k_attn<<<512, 256, 0, stream>>>(QTf, KTb, adj0, adj1, G, out);
  k_tr<<<4096, 256, 0, stream>>>(G, Gt);
  k_gemm<<<1024, 256, 0, stream>>>(G, Gt, out);
}

// Round 9
// 427.189 us; speedup vs baseline: 1.4264x; 1.4264x over previous
//
#include <hip/hip_runtime.h>

typedef unsigned short u16;
typedef unsigned int   u32;

typedef __bf16 bf16x8 __attribute__((ext_vector_type(8)));
typedef float  f32x4  __attribute__((ext_vector_type(4)));

__device__ __forceinline__ float bf2f(u16 u) {
  u32 x = ((u32)u) << 16; float f; __builtin_memcpy(&f, &x, 4); return f;
}
__device__ __forceinline__ u16 f2bf(float f) {
  u32 x; __builtin_memcpy(&x, &f, 4);
  x += 0x7fffu + ((x >> 16) & 1u);
  return (u16)(x >> 16);
}
__device__ __forceinline__ void gl2lds16(const void* g, void* l) {
  __builtin_amdgcn_global_load_lds((const __attribute__((address_space(1))) void*)g,
                                   (__attribute__((address_space(3))) void*)l, 16, 0, 0);
}

// ---------------- K1: hT = relu(X @ W1 + b1)^T, hT:[64][8192] f32 (transposed) ----------------
__global__ __launch_bounds__(256) void k_h(const float* __restrict__ hd, const float* __restrict__ W1,
                                           const float* __restrict__ b1, float* __restrict__ hT)
{
  __shared__ float w1s[12 * 64];
  __shared__ float b1s[64];
  int t = threadIdx.x;
  for (int idx = t; idx < 768; idx += 256) w1s[idx] = W1[idx];
  if (t < 64) b1s[t] = b1[t];
  __syncthreads();
  int i = blockIdx.x * 256 + t;
  int b = i >> 10, n = i & 1023;
  float x[12];
#pragma unroll
  for (int l = 0; l < 12; ++l) x[l] = hd[(b * 12 + l) * 1024 + n];
  float acc[64];
#pragma unroll
  for (int j = 0; j < 64; ++j) acc[j] = b1s[j];
#pragma unroll
  for (int l = 0; l < 12; ++l) {
    float xl = x[l];
#pragma unroll
    for (int j = 0; j < 64; ++j) acc[j] += xl * w1s[l * 64 + j];
  }
#pragma unroll
  for (int j = 0; j < 64; ++j) hT[(size_t)j * 8192 + i] = fmaxf(acc[j], 0.f);
}

// ---------------- K2: BN stats + finalize fused; block j owns column j ----------------
__global__ __launch_bounds__(256) void k_bn(const float* __restrict__ hT, const float* __restrict__ gamma,
                                            const float* __restrict__ beta, float* __restrict__ ss)
{
  int j = blockIdx.x;  // 64 blocks
  int t = threadIdx.x;
  const float* row = hT + (size_t)j * 8192;
  float s = 0.f, q = 0.f;
  for (int it = 0; it < 32; ++it) {
    float v = row[it * 256 + t];
    s += v; q += v * v;
  }
  __shared__ float ls[256], lq[256];
  ls[t] = s; lq[t] = q;
  __syncthreads();
  for (int off = 128; off > 0; off >>= 1) {
    if (t < off) { ls[t] += ls[t + off]; lq[t] += lq[t + off]; }
    __syncthreads();
  }
  if (t == 0) {
    float mu = ls[0] * (1.f / 8192.f);
    float var = lq[0] * (1.f / 8192.f) - mu * mu;
    float inv = rsqrtf(var + 1e-5f);
    float sc = gamma[j] * inv;
    ss[j] = sc;
    ss[64 + j] = beta[j] - mu * sc;
  }
}

// ---------------- K0: embedding parts of Q/K: emb @ W[32:48,:] ----------------
// embpart layout [e][qk][n][32]  (separate kernel: fusing this into k_dyqk spilled to scratch, R8)
__global__ __launch_bounds__(256) void k_emb(const float* __restrict__ embd, const float* __restrict__ embu,
                                             const float* __restrict__ WQ, const float* __restrict__ WK,
                                             float* __restrict__ embpart)
{
  int g = blockIdx.x * 256 + threadIdx.x;  // 131072 total
  int o = g & 31, n = (g >> 5) & 1023, qk = (g >> 15) & 1, e = g >> 16;
  const float* emb = e ? embu : embd;
  const float* W = qk ? WK : WQ;
  float acc = 0.f;
#pragma unroll
  for (int d = 0; d < 16; ++d) acc += emb[n * 16 + d] * W[(32 + d) * 32 + o];
  embpart[g] = acc;
}

// ---------------- K3: dy_feat + Q/K; Q stored f32 transposed, K stored bf16 transposed ------
// Reads hT coalesced; emb parts from precomputed embpart (NOT fused - register budget, R8 lesson).
__global__ __launch_bounds__(256) void k_dyqk(const float* __restrict__ hT, const float* __restrict__ ss,
                                              const float* __restrict__ W2, const float* __restrict__ b2,
                                              const float* __restrict__ WQ, const float* __restrict__ WK,
                                              const float* __restrict__ embpart,
                                              float* __restrict__ QTf, u16* __restrict__ KTb)
{
  __shared__ float w2s[64 * 32], wqs[32 * 32], wks[32 * 32], b2s[32], scs[64], shs[64];
  int t = threadIdx.x;
  for (int idx = t; idx < 2048; idx += 256) w2s[idx] = W2[idx];
  for (int idx = t; idx < 1024; idx += 256) { wqs[idx] = WQ[idx]; wks[idx] = WK[idx]; }
  if (t < 32) b2s[t] = b2[t];
  if (t < 64) { scs[t] = ss[t]; shs[t] = ss[64 + t]; }
  __syncthreads();
  int i = blockIdx.x * 256 + t;
  int b = i >> 10, n = i & 1023;
  float dy[32];
#pragma unroll
  for (int o = 0; o < 32; ++o) dy[o] = b2s[o];
  for (int j = 0; j < 64; ++j) {
    float hj = hT[(size_t)j * 8192 + i] * scs[j] + shs[j];  // coalesced over i
#pragma unroll
    for (int o = 0; o < 32; ++o) dy[o] += hj * w2s[j * 32 + o];
  }
  float tq[32], tk[32];
#pragma unroll
  for (int o = 0; o < 32; ++o) { tq[o] = 0.f; tk[o] = 0.f; }
  for (int j = 0; j < 32; ++j) {
    float d = dy[j];
#pragma unroll
    for (int o = 0; o < 32; ++o) { tq[o] += d * wqs[j * 32 + o]; tk[o] += d * wks[j * 32 + o]; }
  }
#pragma unroll
  for (int e = 0; e < 2; ++e) {
    const float* epQ = embpart + ((size_t)(e * 2 + 0) * 1024 + n) * 32;
    const float* epK = embpart + ((size_t)(e * 2 + 1) * 1024 + n) * 32;
    size_t qb = ((size_t)(e * 8 + b) * 32) * 1024 + n;
#pragma unroll
    for (int o = 0; o < 32; ++o) {
      QTf[qb + (size_t)o * 1024] = tq[o] + epQ[o];          // coalesced over n
      KTb[qb + (size_t)o * 1024] = f2bf(tk[o] + epK[o]);
    }
  }
}

// ---------------- K5: fused logits/exp/mask/row-normalize + order-1 output + G ----------------
// softmax denominator cancels against row normalization; logits are O(1) so no max-subtraction.
__global__ __launch_bounds__(256) void k_attn(const float* __restrict__ QTf, const u16* __restrict__ KTb,
                                              const float* __restrict__ adj0, const float* __restrict__ adj1,
                                              u16* __restrict__ G, float* __restrict__ out)
{
  int blk = (blockIdx.x & 7) * 64 + (blockIdx.x >> 3);  // T1 chunked swizzle, 512 wgs
  int rg = blk & 31, b = (blk >> 5) & 7, e = blk >> 8;
  int t = threadIdx.x;
  int eb = e * 8 + b;
  int wv = t >> 6, lane = t & 63;
  const float* adj = e ? adj1 : adj0;
  const u16* Kp = KTb + ((size_t)eb << 15);      // [h][m] bf16 slab, 64 KB, L2-resident
  const float* Qp = QTf + ((size_t)eb << 15);
  u16* Gp = G + ((size_t)eb << 20);
  float* o1 = out + (((size_t)(2 * e) * 8 + b) << 21);
  const float sc = 0.17677669529663687f;  // 1/sqrt(32)
#pragma unroll
  for (int grp = 0; grp < 2; ++grp) {
    int r0 = rg * 32 + wv * 8 + grp * 4;  // 4 rows per group
    float accA[4][8], accB[4][8];
#pragma unroll
    for (int r = 0; r < 4; ++r)
#pragma unroll
      for (int k = 0; k < 8; ++k) { accA[r][k] = 0.f; accB[r][k] = 0.f; }
    for (int hh = 0; hh < 32; ++hh) {
      float4 qv = *(const float4*)(Qp + hh * 1024 + r0);
      uint4 ka = *(const uint4*)(Kp + hh * 1024 + lane * 8);        // m = lane*8 .. +7
      uint4 kb = *(const uint4*)(Kp + hh * 1024 + 512 + lane * 8);  // m = 512 + lane*8 .. +7
      float kf[8] = {bf2f((u16)ka.x), bf2f((u16)(ka.x >> 16)), bf2f((u16)ka.y), bf2f((u16)(ka.y >> 16)),
                     bf2f((u16)ka.z), bf2f((u16)(ka.z >> 16)), bf2f((u16)ka.w), bf2f((u16)(ka.w >> 16))};
      float kg[8] = {bf2f((u16)kb.x), bf2f((u16)(kb.x >> 16)), bf2f((u16)kb.y), bf2f((u16)(kb.y >> 16)),
                     bf2f((u16)kb.z), bf2f((u16)(kb.z >> 16)), bf2f((u16)kb.w), bf2f((u16)(kb.w >> 16))};
#pragma unroll
      for (int k = 0; k < 8; ++k) {
        accA[0][k] += qv.x * kf[k]; accA[1][k] += qv.y * kf[k];
        accA[2][k] += qv.z * kf[k]; accA[3][k] += qv.w * kf[k];
        accB[0][k] += qv.x * kg[k]; accB[1][k] += qv.y * kg[k];
        accB[2][k] += qv.z * kg[k]; accB[3][k] += qv.w * kg[k];
      }
    }
#pragma unroll
    for (int r = 0; r < 4; ++r) {
      int gr = r0 + r;
      const float* arow = adj + ((size_t)gr << 10);
      int mA = lane * 8, mB = 512 + lane * 8;
      float4 a0 = *(const float4*)(arow + mA);
      float4 a1 = *(const float4*)(arow + mA + 4);
      float4 c0 = *(const float4*)(arow + mB);
      float4 c1 = *(const float4*)(arow + mB + 4);
      float af[8] = {a0.x, a0.y, a0.z, a0.w, a1.x, a1.y, a1.z, a1.w};
      float bfv[8] = {c0.x, c0.y, c0.z, c0.w, c1.x, c1.y, c1.z, c1.w};
      float ta[8], tb[8];
      float p = 0.f;
#pragma unroll
      for (int k = 0; k < 8; ++k) { ta[k] = (af[k] + 1e-7f) * __expf(accA[r][k] * sc); p += ta[k]; }
#pragma unroll
      for (int k = 0; k < 8; ++k) { tb[k] = (bfv[k] + 1e-7f) * __expf(accB[r][k] * sc); p += tb[k]; }
#pragma unroll
      for (int off = 32; off > 0; off >>= 1) p += __shfl_xor(p, off);
      float inv = 1.f / p;
      if (!__builtin_isfinite(inv)) inv = 0.f;
      float ga[8], gb[8];
#pragma unroll
      for (int k = 0; k < 8; ++k) { ga[k] = ta[k] * inv; gb[k] = tb[k] * inv; }
      // G row with diagonal intact (needed for g@g), bf16
      uint4 pa, pb;
      pa.x = f2bf(ga[0]) | ((u32)f2bf(ga[1]) << 16);  pa.y = f2bf(ga[2]) | ((u32)f2bf(ga[3]) << 16);
      pa.z = f2bf(ga[4]) | ((u32)f2bf(ga[5]) << 16);  pa.w = f2bf(ga[6]) | ((u32)f2bf(ga[7]) << 16);
      pb.x = f2bf(gb[0]) | ((u32)f2bf(gb[1]) << 16);  pb.y = f2bf(gb[2]) | ((u32)f2bf(gb[3]) << 16);
      pb.z = f2bf(gb[4]) | ((u32)f2bf(gb[5]) << 16);  pb.w = f2bf(gb[6]) | ((u32)f2bf(gb[7]) << 16);
      *(uint4*)(Gp + ((size_t)gr << 10) + mA) = pa;
      *(uint4*)(Gp + ((size_t)gr << 10) + mB) = pb;
      // order-1 output: zero diag, row duplicated, f32
#pragma unroll
      for (int k = 0; k < 8; ++k) {
        if (mA + k == gr) ga[k] = 0.f;
        if (mB + k == gr) gb[k] = 0.f;
      }
      size_t ob = (size_t)gr << 11;
      float4 fa0 = {ga[0], ga[1], ga[2], ga[3]}, fa1 = {ga[4], ga[5], ga[6], ga[7]};
      float4 fb0 = {gb[0], gb[1], gb[2], gb[3]}, fb1 = {gb[4], gb[5], gb[6], gb[7]};
      *(float4*)(o1 + ob + mA) = fa0;         *(float4*)(o1 + ob + mA + 4) = fa1;
      *(float4*)(o1 + ob + mB) = fb0;         *(float4*)(o1 + ob + mB + 4) = fb1;
      *(float4*)(o1 + ob + 1024 + mA) = fa0;  *(float4*)(o1 + ob + 1024 + mA + 4) = fa1;
      *(float4*)(o1 + ob + 1024 + mB) = fb0;  *(float4*)(o1 + ob + 1024 + mB + 4) = fb1;
    }
  }
}

// ---------------- K5t: G -> Gt (64x64 LDS tile transpose, pad 66 to dodge bank conflicts) -----
__global__ __launch_bounds__(256) void k_tr(const u16* __restrict__ G, u16* __restrict__ Gt)
{
  __shared__ u16 tile[64 * 66];
  int blk = blockIdx.x;
  int mat = blk >> 8, tl = blk & 255, ti = tl >> 4, tj = tl & 15;
  size_t mo = (size_t)mat << 20;
  int t = threadIdx.x;
#pragma unroll
  for (int half = 0; half < 2; ++half) {
    int idx = t + half * 256;
    int row = idx >> 3, q = idx & 7;
    uint4 v = *(const uint4*)(G + mo + (size_t)(ti * 64 + row) * 1024 + tj * 64 + q * 8);
    u16* d = &tile[row * 66 + q * 8];
    d[0] = (u16)v.x; d[1] = (u16)(v.x >> 16);
    d[2] = (u16)v.y; d[3] = (u16)(v.y >> 16);
    d[4] = (u16)v.z; d[5] = (u16)(v.z >> 16);
    d[6] = (u16)v.w; d[7] = (u16)(v.w >> 16);
  }
  __syncthreads();
#pragma unroll
  for (int half = 0; half < 2; ++half) {
    int idx = t + half * 256;
    int row = idx >> 3, q = idx & 7;
    u16 s0 = tile[(q * 8 + 0) * 66 + row], s1 = tile[(q * 8 + 1) * 66 + row];
    u16 s2 = tile[(q * 8 + 2) * 66 + row], s3 = tile[(q * 8 + 3) * 66 + row];
    u16 s4 = tile[(q * 8 + 4) * 66 + row], s5 = tile[(q * 8 + 5) * 66 + row];
    u16 s6 = tile[(q * 8 + 6) * 66 + row], s7 = tile[(q * 8 + 7) * 66 + row];
    uint4 v;
    v.x = s0 | ((u32)s1 << 16); v.y = s2 | ((u32)s3 << 16);
    v.z = s4 | ((u32)s5 << 16); v.w = s6 | ((u32)s7 << 16);
    *(uint4*)(Gt + mo + (size_t)(tj * 64 + row) * 1024 + ti * 64 + q * 8) = v;
  }
}

// ---------------- K6: batched C = G@G via bf16 MFMA; order-2 output fused in epilogue --------
// 2-phase double-buffered staging (R6 measured-best form): prefetch next K-tile before compute,
// one __syncthreads per K-step.
__global__ __launch_bounds__(256) void k_gemm(const u16* __restrict__ G, const u16* __restrict__ Gt,
                                              float* __restrict__ out)
{
  __shared__ __align__(16) u16 As[2][128 * 32];
  __shared__ __align__(16) u16 Bs[2][128 * 32];
  int bid = (blockIdx.x & 7) * 128 + (blockIdx.x >> 3);  // T1 chunked swizzle, 1024 wgs
  int mat = bid >> 6, tile = bid & 63, ti = tile >> 3, tj = tile & 7;
  size_t mo = (size_t)mat << 20;
  const u16* A = G + mo;
  const u16* Bm = Gt + mo;  // Bt[n][k] = G[k][n]
  int t = threadIdx.x;
  int w = t >> 6, lane = t & 63;
  int quad = lane >> 4, l16 = lane & 15;
  int wr = (w & 1) * 64, wc = (w >> 1) * 64;
  f32x4 acc[4][4];
#pragma unroll
  for (int i = 0; i < 4; ++i)
#pragma unroll
    for (int j = 0; j < 4; ++j) acc[i][j] = f32x4{0.f, 0.f, 0.f, 0.f};

#define STAGE(buf, kk)                                                                  \
  {                                                                                     \
    _Pragma("unroll")                                                                   \
    for (int it = 0; it < 2; ++it) {                                                    \
      int sbase = (it * 4 + w) * 64;                                                    \
      int r = (sbase + lane) >> 2, c = (sbase + lane) & 3;                              \
      gl2lds16(A + (size_t)(ti * 128 + r) * 1024 + (kk) + c * 8,                        \
               (u16*)As[buf] + (size_t)sbase * 8);                                      \
      gl2lds16(Bm + (size_t)(tj * 128 + r) * 1024 + (kk) + c * 8,                       \
               (u16*)Bs[buf] + (size_t)sbase * 8);                                      \
    }                                                                                   \
  }

  STAGE(0, 0);
  __syncthreads();
  int cur = 0;
  for (int k0 = 0; k0 < 1024; k0 += 32) {
    if (k0 + 32 < 1024) STAGE(cur ^ 1, k0 + 32);   // prefetch overlaps compute below
    bf16x8 af[4], bfr[4];
#pragma unroll
    for (int mt = 0; mt < 4; ++mt)
      af[mt] = *(const bf16x8*)&As[cur][(wr + mt * 16 + l16) * 32 + quad * 8];
#pragma unroll
    for (int nt = 0; nt < 4; ++nt)
      bfr[nt] = *(const bf16x8*)&Bs[cur][(wc + nt * 16 + l16) * 32 + quad * 8];
#pragma unroll
    for (int mt = 0; mt < 4; ++mt)
#pragma unroll
      for (int nt = 0; nt < 4; ++nt)
        acc[mt][nt] = __builtin_amdgcn_mfma_f32_16x16x32_bf16(af[mt], bfr[nt], acc[mt][nt], 0, 0, 0);
    __syncthreads();  // drains vmcnt (prefetch done) + lgkmcnt (ds_reads done) for all waves
    cur ^= 1;
  }
#undef STAGE
  int e = mat >> 3, bb = mat & 7;
  float* o2 = out + (((size_t)(2 * e + 1) * 8 + bb) << 21);
#pragma unroll
  for (int mt = 0; mt < 4; ++mt)
#pragma unroll
    for (int r = 0; r < 4; ++r) {
      int gr = ti * 128 + wr + mt * 16 + quad * 4 + r;
      size_t rb = (size_t)gr << 11;
#pragma unroll
      for (int nt = 0; nt < 4; ++nt) {
        int gc = tj * 128 + wc + nt * 16 + l16;
        float v = (gr == gc) ? 0.f : acc[mt][nt][r];
        o2[rb + gc] = v;
        o2[rb + 1024 + gc] = v;
      }
    }
}

extern "C" void kernel_launch(void* const* d_in, const int* in_sizes, int n_in,
                              void* d_out, int out_size, void* d_ws, size_t ws_size,
                              hipStream_t stream) {
  const float* hd    = (const float*)d_in[0];
  const float* embd  = (const float*)d_in[1];
  const float* embu  = (const float*)d_in[2];
  const float* adj0  = (const float*)d_in[3];
  const float* adj1  = (const float*)d_in[4];
  const float* W1    = (const float*)d_in[5];
  const float* b1    = (const float*)d_in[6];
  const float* gamma = (const float*)d_in[7];
  const float* beta  = (const float*)d_in[8];
  const float* W2    = (const float*)d_in[9];
  const float* b2    = (const float*)d_in[10];
  const float* WQ    = (const float*)d_in[11];
  const float* WK    = (const float*)d_in[12];
  char* ws = (char*)d_ws;
  float* ss      = (float*)(ws + 1024);      // 128 f32 (scale, shift)
  float* embpart = (float*)(ws + 4096);      // [2][2][1024][32] f32       (512 KB)
  float* hT      = (float*)(ws + 528384);    // [64][8192] f32 transposed  (2 MB)
  float* QTf     = (float*)(ws + 2625536);   // [16][32][1024] f32         (2 MB)
  u16* KTb       = (u16*)(ws + 4722688);     // [16][32][1024] bf16        (1 MB)
  u16* G         = (u16*)(ws + 5771264);     // [16][1024][1024] bf16      (32 MB)
  u16* Gt        = (u16*)(ws + 39325696);    // transpose                  (32 MB)
  float* out     = (float*)d_out;

  k_h<<<32, 256, 0, stream>>>(hd, W1, b1, hT);
  k_bn<<<64, 256, 0, stream>>>(hT, gamma, beta, ss);
  k_emb<<<512, 256, 0, stream>>>(embd, embu, WQ, WK, embpart);
  k_dyqk<<<32, 256, 0, stream>>>(hT, ss, W2, b2, WQ, WK, embpart, QTf, KTb);
  k_attn<<<512, 256, 0, stream>>>(QTf, KTb, adj0, adj1, G, out);
  k_tr<<<4096, 256, 0, stream>>>(G, Gt);
  k_gemm<<<1024, 256, 0, stream>>>(G, Gt, out);
}

// Round 11
// 416.793 us; speedup vs baseline: 1.4619x; 1.0249x over previous
//
#include <hip/hip_runtime.h>

typedef unsigned short u16;
typedef unsigned int   u32;

typedef __bf16 bf16x8 __attribute__((ext_vector_type(8)));
typedef float  f32x4  __attribute__((ext_vector_type(4)));

__device__ __forceinline__ float bf2f(u16 u) {
  u32 x = ((u32)u) << 16; float f; __builtin_memcpy(&f, &x, 4); return f;
}
__device__ __forceinline__ u16 f2bf(float f) {
  u32 x; __builtin_memcpy(&x, &f, 4);
  x += 0x7fffu + ((x >> 16) & 1u);
  return (u16)(x >> 16);
}
__device__ __forceinline__ void gl2lds16(const void* g, void* l) {
  __builtin_amdgcn_global_load_lds((const __attribute__((address_space(1))) void*)g,
                                   (__attribute__((address_space(3))) void*)l, 16, 0, 0);
}

// ---------------- K1: h = relu(X @ W1 + b1), h:[8192,64] f32 ----------------
__global__ __launch_bounds__(256) void k_h(const float* __restrict__ hd, const float* __restrict__ W1,
                                           const float* __restrict__ b1, float* __restrict__ h)
{
  __shared__ float w1s[12 * 64];
  __shared__ float b1s[64];
  int t = threadIdx.x;
  for (int idx = t; idx < 768; idx += 256) w1s[idx] = W1[idx];
  if (t < 64) b1s[t] = b1[t];
  __syncthreads();
  int i = blockIdx.x * 256 + t;
  int b = i >> 10, n = i & 1023;
  float x[12];
#pragma unroll
  for (int l = 0; l < 12; ++l) x[l] = hd[(b * 12 + l) * 1024 + n];
  float acc[64];
#pragma unroll
  for (int j = 0; j < 64; ++j) acc[j] = b1s[j];
#pragma unroll
  for (int l = 0; l < 12; ++l) {
    float xl = x[l];
#pragma unroll
    for (int j = 0; j < 64; ++j) acc[j] += xl * w1s[l * 64 + j];
  }
  float4* hv = (float4*)(h + (size_t)i * 64);
#pragma unroll
  for (int j4 = 0; j4 < 16; ++j4) {
    float4 v;
    v.x = fmaxf(acc[j4 * 4 + 0], 0.f);
    v.y = fmaxf(acc[j4 * 4 + 1], 0.f);
    v.z = fmaxf(acc[j4 * 4 + 2], 0.f);
    v.w = fmaxf(acc[j4 * 4 + 3], 0.f);
    hv[j4] = v;
  }
}

// ---------------- K2a: column sums/sumsq of h (BN stats) ----------------
__global__ __launch_bounds__(256) void k_stats(const float* __restrict__ h, float* __restrict__ stats)
{
  int t = threadIdx.x;
  size_t base = (size_t)blockIdx.x * 8192;
  float s = 0.f, sq = 0.f;
  for (int it = 0; it < 32; ++it) {
    float v = h[base + it * 256 + t];  // column = t & 63, invariant over it
    s += v; sq += v * v;
  }
  __shared__ float ls[256], lq[256];
  ls[t] = s; lq[t] = sq;
  __syncthreads();
  if (t < 64) {
    float S = ls[t] + ls[t + 64] + ls[t + 128] + ls[t + 192];
    float Q = lq[t] + lq[t + 64] + lq[t + 128] + lq[t + 192];
    atomicAdd(&stats[t], S);
    atomicAdd(&stats[64 + t], Q);
  }
}

// ---------------- K2b: finalize BN scale/shift ----------------
__global__ void k_finalize(const float* __restrict__ stats, const float* __restrict__ gamma,
                           const float* __restrict__ beta, float* __restrict__ ss)
{
  int t = threadIdx.x;  // 64 threads
  float mu = stats[t] * (1.f / 8192.f);
  float var = stats[64 + t] * (1.f / 8192.f) - mu * mu;
  float inv = rsqrtf(var + 1e-5f);
  float sc = gamma[t] * inv;
  ss[t] = sc;
  ss[64 + t] = beta[t] - mu * sc;
}

// ---------------- K0: embedding parts of Q/K: emb @ W[32:48,:] ----------------
// embpart layout [e][qk][n][32]
__global__ __launch_bounds__(256) void k_emb(const float* __restrict__ embd, const float* __restrict__ embu,
                                             const float* __restrict__ WQ, const float* __restrict__ WK,
                                             float* __restrict__ embpart)
{
  int g = blockIdx.x * 256 + threadIdx.x;  // 131072 total
  int o = g & 31, n = (g >> 5) & 1023, qk = (g >> 15) & 1, e = g >> 16;
  const float* emb = e ? embu : embd;
  const float* W = qk ? WK : WQ;
  float acc = 0.f;
#pragma unroll
  for (int d = 0; d < 16; ++d) acc += emb[n * 16 + d] * W[(32 + d) * 32 + o];
  embpart[g] = acc;
}

// ---------------- K3: dy_feat + Q/K; Q stored f32 transposed, K stored bf16 transposed ------
__global__ __launch_bounds__(256) void k_dyqk(const float* __restrict__ h, const float* __restrict__ ss,
                                              const float* __restrict__ W2, const float* __restrict__ b2,
                                              const float* __restrict__ WQ, const float* __restrict__ WK,
                                              const float* __restrict__ embpart,
                                              float* __restrict__ QTf, u16* __restrict__ KTb)
{
  __shared__ float w2s[64 * 32], wqs[32 * 32], wks[32 * 32], b2s[32], scs[64], shs[64];
  int t = threadIdx.x;
  for (int idx = t; idx < 2048; idx += 256) w2s[idx] = W2[idx];
  for (int idx = t; idx < 1024; idx += 256) { wqs[idx] = WQ[idx]; wks[idx] = WK[idx]; }
  if (t < 32) b2s[t] = b2[t];
  if (t < 64) { scs[t] = ss[t]; shs[t] = ss[64 + t]; }
  __syncthreads();
  int i = blockIdx.x * 256 + t;
  int b = i >> 10, n = i & 1023;
  float dy[32];
#pragma unroll
  for (int o = 0; o < 32; ++o) dy[o] = b2s[o];
  for (int j = 0; j < 64; ++j) {
    float hj = h[(size_t)i * 64 + j] * scs[j] + shs[j];
#pragma unroll
    for (int o = 0; o < 32; ++o) dy[o] += hj * w2s[j * 32 + o];
  }
  float tq[32], tk[32];
#pragma unroll
  for (int o = 0; o < 32; ++o) { tq[o] = 0.f; tk[o] = 0.f; }
  for (int j = 0; j < 32; ++j) {
    float d = dy[j];
#pragma unroll
    for (int o = 0; o < 32; ++o) { tq[o] += d * wqs[j * 32 + o]; tk[o] += d * wks[j * 32 + o]; }
  }
#pragma unroll
  for (int e = 0; e < 2; ++e) {
    const float* epQ = embpart + ((size_t)(e * 2 + 0) * 1024 + n) * 32;
    const float* epK = embpart + ((size_t)(e * 2 + 1) * 1024 + n) * 32;
    size_t qb = ((size_t)(e * 8 + b) * 32) * 1024 + n;
#pragma unroll
    for (int o = 0; o < 32; ++o) {
      QTf[qb + (size_t)o * 1024] = tq[o] + epQ[o];          // coalesced over n
      KTb[qb + (size_t)o * 1024] = f2bf(tk[o] + epK[o]);
    }
  }
}

// ---------------- K5: fused logits/exp/mask/row-normalize + order-1 output + G ----------------
// softmax denominator cancels against row normalization; logits are O(1) so no max-subtraction.
__global__ __launch_bounds__(256) void k_attn(const float* __restrict__ QTf, const u16* __restrict__ KTb,
                                              const float* __restrict__ adj0, const float* __restrict__ adj1,
                                              u16* __restrict__ G, float* __restrict__ out)
{
  int blk = (blockIdx.x & 7) * 64 + (blockIdx.x >> 3);  // T1 chunked swizzle, 512 wgs
  int rg = blk & 31, b = (blk >> 5) & 7, e = blk >> 8;
  int t = threadIdx.x;
  int eb = e * 8 + b;
  int wv = t >> 6, lane = t & 63;
  const float* adj = e ? adj1 : adj0;
  const u16* Kp = KTb + ((size_t)eb << 15);      // [h][m] bf16 slab, 64 KB, L2-resident
  const float* Qp = QTf + ((size_t)eb << 15);
  u16* Gp = G + ((size_t)eb << 20);
  float* o1 = out + (((size_t)(2 * e) * 8 + b) << 21);
  const float sc = 0.17677669529663687f;  // 1/sqrt(32)
#pragma unroll
  for (int grp = 0; grp < 2; ++grp) {
    int r0 = rg * 32 + wv * 8 + grp * 4;  // 4 rows per group
    float accA[4][8], accB[4][8];
#pragma unroll
    for (int r = 0; r < 4; ++r)
#pragma unroll
      for (int k = 0; k < 8; ++k) { accA[r][k] = 0.f; accB[r][k] = 0.f; }
    for (int hh = 0; hh < 32; ++hh) {
      float4 qv = *(const float4*)(Qp + hh * 1024 + r0);
      uint4 ka = *(const uint4*)(Kp + hh * 1024 + lane * 8);        // m = lane*8 .. +7
      uint4 kb = *(const uint4*)(Kp + hh * 1024 + 512 + lane * 8);  // m = 512 + lane*8 .. +7
      float kf[8] = {bf2f((u16)ka.x), bf2f((u16)(ka.x >> 16)), bf2f((u16)ka.y), bf2f((u16)(ka.y >> 16)),
                     bf2f((u16)ka.z), bf2f((u16)(ka.z >> 16)), bf2f((u16)ka.w), bf2f((u16)(ka.w >> 16))};
      float kg[8] = {bf2f((u16)kb.x), bf2f((u16)(kb.x >> 16)), bf2f((u16)kb.y), bf2f((u16)(kb.y >> 16)),
                     bf2f((u16)kb.z), bf2f((u16)(kb.z >> 16)), bf2f((u16)kb.w), bf2f((u16)(kb.w >> 16))};
#pragma unroll
      for (int k = 0; k < 8; ++k) {
        accA[0][k] += qv.x * kf[k]; accA[1][k] += qv.y * kf[k];
        accA[2][k] += qv.z * kf[k]; accA[3][k] += qv.w * kf[k];
        accB[0][k] += qv.x * kg[k]; accB[1][k] += qv.y * kg[k];
        accB[2][k] += qv.z * kg[k]; accB[3][k] += qv.w * kg[k];
      }
    }
#pragma unroll
    for (int r = 0; r < 4; ++r) {
      int gr = r0 + r;
      const float* arow = adj + ((size_t)gr << 10);
      int mA = lane * 8, mB = 512 + lane * 8;
      float4 a0 = *(const float4*)(arow + mA);
      float4 a1 = *(const float4*)(arow + mA + 4);
      float4 c0 = *(const float4*)(arow + mB);
      float4 c1 = *(const float4*)(arow + mB + 4);
      float af[8] = {a0.x, a0.y, a0.z, a0.w, a1.x, a1.y, a1.z, a1.w};
      float bfv[8] = {c0.x, c0.y, c0.z, c0.w, c1.x, c1.y, c1.z, c1.w};
      float ta[8], tb[8];
      float p = 0.f;
#pragma unroll
      for (int k = 0; k < 8; ++k) { ta[k] = (af[k] + 1e-7f) * __expf(accA[r][k] * sc); p += ta[k]; }
#pragma unroll
      for (int k = 0; k < 8; ++k) { tb[k] = (bfv[k] + 1e-7f) * __expf(accB[r][k] * sc); p += tb[k]; }
#pragma unroll
      for (int off = 32; off > 0; off >>= 1) p += __shfl_xor(p, off);
      float inv = 1.f / p;
      if (!__builtin_isfinite(inv)) inv = 0.f;
      float ga[8], gb[8];
#pragma unroll
      for (int k = 0; k < 8; ++k) { ga[k] = ta[k] * inv; gb[k] = tb[k] * inv; }
      // G row with diagonal intact (needed for g@g), bf16
      uint4 pa, pb;
      pa.x = f2bf(ga[0]) | ((u32)f2bf(ga[1]) << 16);  pa.y = f2bf(ga[2]) | ((u32)f2bf(ga[3]) << 16);
      pa.z = f2bf(ga[4]) | ((u32)f2bf(ga[5]) << 16);  pa.w = f2bf(ga[6]) | ((u32)f2bf(ga[7]) << 16);
      pb.x = f2bf(gb[0]) | ((u32)f2bf(gb[1]) << 16);  pb.y = f2bf(gb[2]) | ((u32)f2bf(gb[3]) << 16);
      pb.z = f2bf(gb[4]) | ((u32)f2bf(gb[5]) << 16);  pb.w = f2bf(gb[6]) | ((u32)f2bf(gb[7]) << 16);
      *(uint4*)(Gp + ((size_t)gr << 10) + mA) = pa;
      *(uint4*)(Gp + ((size_t)gr << 10) + mB) = pb;
      // order-1 output: zero diag, row duplicated, f32
#pragma unroll
      for (int k = 0; k < 8; ++k) {
        if (mA + k == gr) ga[k] = 0.f;
        if (mB + k == gr) gb[k] = 0.f;
      }
      size_t ob = (size_t)gr << 11;
      float4 fa0 = {ga[0], ga[1], ga[2], ga[3]}, fa1 = {ga[4], ga[5], ga[6], ga[7]};
      float4 fb0 = {gb[0], gb[1], gb[2], gb[3]}, fb1 = {gb[4], gb[5], gb[6], gb[7]};
      *(float4*)(o1 + ob + mA) = fa0;         *(float4*)(o1 + ob + mA + 4) = fa1;
      *(float4*)(o1 + ob + mB) = fb0;         *(float4*)(o1 + ob + mB + 4) = fb1;
      *(float4*)(o1 + ob + 1024 + mA) = fa0;  *(float4*)(o1 + ob + 1024 + mA + 4) = fa1;
      *(float4*)(o1 + ob + 1024 + mB) = fb0;  *(float4*)(o1 + ob + 1024 + mB + 4) = fb1;
    }
  }
}

// ---------------- K5t: G -> Gt (64x64 LDS tile transpose, pad 66 to dodge bank conflicts) -----
// XCD-chunked swizzle aligned with k_attn (writer) and k_gemm (reader): XCD x owns mats 2x,2x+1,
// so the G read hits the same XCD's L2 that k_attn just wrote, and Gt stays resident for k_gemm.
__global__ __launch_bounds__(256) void k_tr(const u16* __restrict__ G, u16* __restrict__ Gt)
{
  __shared__ u16 tile[64 * 66];
  int blk = (blockIdx.x & 7) * 512 + (blockIdx.x >> 3);  // T1 chunked swizzle, 4096 wgs
  int mat = blk >> 8, tl = blk & 255, ti = tl >> 4, tj = tl & 15;
  size_t mo = (size_t)mat << 20;
  int t = threadIdx.x;
#pragma unroll
  for (int half = 0; half < 2; ++half) {
    int idx = t + half * 256;
    int row = idx >> 3, q = idx & 7;
    uint4 v = *(const uint4*)(G + mo + (size_t)(ti * 64 + row) * 1024 + tj * 64 + q * 8);
    u16* d = &tile[row * 66 + q * 8];
    d[0] = (u16)v.x; d[1] = (u16)(v.x >> 16);
    d[2] = (u16)v.y; d[3] = (u16)(v.y >> 16);
    d[4] = (u16)v.z; d[5] = (u16)(v.z >> 16);
    d[6] = (u16)v.w; d[7] = (u16)(v.w >> 16);
  }
  __syncthreads();
#pragma unroll
  for (int half = 0; half < 2; ++half) {
    int idx = t + half * 256;
    int row = idx >> 3, q = idx & 7;
    u16 s0 = tile[(q * 8 + 0) * 66 + row], s1 = tile[(q * 8 + 1) * 66 + row];
    u16 s2 = tile[(q * 8 + 2) * 66 + row], s3 = tile[(q * 8 + 3) * 66 + row];
    u16 s4 = tile[(q * 8 + 4) * 66 + row], s5 = tile[(q * 8 + 5) * 66 + row];
    u16 s6 = tile[(q * 8 + 6) * 66 + row], s7 = tile[(q * 8 + 7) * 66 + row];
    uint4 v;
    v.x = s0 | ((u32)s1 << 16); v.y = s2 | ((u32)s3 << 16);
    v.z = s4 | ((u32)s5 << 16); v.w = s6 | ((u32)s7 << 16);
    *(uint4*)(Gt + mo + (size_t)(tj * 64 + row) * 1024 + ti * 64 + q * 8) = v;
  }
}

// ---------------- K6: batched C = G@G via bf16 MFMA; order-2 output fused in epilogue --------
// 2-phase double-buffered staging (R6 measured-best form): prefetch next K-tile before compute,
// one __syncthreads per K-step.
__global__ __launch_bounds__(256) void k_gemm(const u16* __restrict__ G, const u16* __restrict__ Gt,
                                              float* __restrict__ out)
{
  __shared__ __align__(16) u16 As[2][128 * 32];
  __shared__ __align__(16) u16 Bs[2][128 * 32];
  int bid = (blockIdx.x & 7) * 128 + (blockIdx.x >> 3);  // T1 chunked swizzle, 1024 wgs
  int mat = bid >> 6, tile = bid & 63, ti = tile >> 3, tj = tile & 7;
  size_t mo = (size_t)mat << 20;
  const u16* A = G + mo;
  const u16* Bm = Gt + mo;  // Bt[n][k] = G[k][n]
  int t = threadIdx.x;
  int w = t >> 6, lane = t & 63;
  int quad = lane >> 4, l16 = lane & 15;
  int wr = (w & 1) * 64, wc = (w >> 1) * 64;
  f32x4 acc[4][4];
#pragma unroll
  for (int i = 0; i < 4; ++i)
#pragma unroll
    for (int j = 0; j < 4; ++j) acc[i][j] = f32x4{0.f, 0.f, 0.f, 0.f};

#define STAGE(buf, kk)                                                                  \
  {                                                                                     \
    _Pragma("unroll")                                                                   \
    for (int it = 0; it < 2; ++it) {                                                    \
      int sbase = (it * 4 + w) * 64;                                                    \
      int r = (sbase + lane) >> 2, c = (sbase + lane) & 3;                              \
      gl2lds16(A + (size_t)(ti * 128 + r) * 1024 + (kk) + c * 8,                        \
               (u16*)As[buf] + (size_t)sbase * 8);                                      \
      gl2lds16(Bm + (size_t)(tj * 128 + r) * 1024 + (kk) + c * 8,                       \
               (u16*)Bs[buf] + (size_t)sbase * 8);                                      \
    }                                                                                   \
  }

  STAGE(0, 0);
  __syncthreads();
  int cur = 0;
  for (int k0 = 0; k0 < 1024; k0 += 32) {
    if (k0 + 32 < 1024) STAGE(cur ^ 1, k0 + 32);   // prefetch overlaps compute below
    bf16x8 af[4], bfr[4];
#pragma unroll
    for (int mt = 0; mt < 4; ++mt)
      af[mt] = *(const bf16x8*)&As[cur][(wr + mt * 16 + l16) * 32 + quad * 8];
#pragma unroll
    for (int nt = 0; nt < 4; ++nt)
      bfr[nt] = *(const bf16x8*)&Bs[cur][(wc + nt * 16 + l16) * 32 + quad * 8];
#pragma unroll
    for (int mt = 0; mt < 4; ++mt)
#pragma unroll
      for (int nt = 0; nt < 4; ++nt)
        acc[mt][nt] = __builtin_amdgcn_mfma_f32_16x16x32_bf16(af[mt], bfr[nt], acc[mt][nt], 0, 0, 0);
    __syncthreads();  // drains vmcnt (prefetch done) + lgkmcnt (ds_reads done) for all waves
    cur ^= 1;
  }
#undef STAGE
  int e = mat >> 3, bb = mat & 7;
  float* o2 = out + (((size_t)(2 * e + 1) * 8 + bb) << 21);
#pragma unroll
  for (int mt = 0; mt < 4; ++mt)
#pragma unroll
    for (int r = 0; r < 4; ++r) {
      int gr = ti * 128 + wr + mt * 16 + quad * 4 + r;
      size_t rb = (size_t)gr << 11;
#pragma unroll
      for (int nt = 0; nt < 4; ++nt) {
        int gc = tj * 128 + wc + nt * 16 + l16;
        float v = (gr == gc) ? 0.f : acc[mt][nt][r];
        o2[rb + gc] = v;
        o2[rb + 1024 + gc] = v;
      }
    }
}

extern "C" void kernel_launch(void* const* d_in, const int* in_sizes, int n_in,
                              void* d_out, int out_size, void* d_ws, size_t ws_size,
                              hipStream_t stream) {
  const float* hd    = (const float*)d_in[0];
  const float* embd  = (const float*)d_in[1];
  const float* embu  = (const float*)d_in[2];
  const float* adj0  = (const float*)d_in[3];
  const float* adj1  = (const float*)d_in[4];
  const float* W1    = (const float*)d_in[5];
  const float* b1    = (const float*)d_in[6];
  const float* gamma = (const float*)d_in[7];
  const float* beta  = (const float*)d_in[8];
  const float* W2    = (const float*)d_in[9];
  const float* b2    = (const float*)d_in[10];
  const float* WQ    = (const float*)d_in[11];
  const float* WK    = (const float*)d_in[12];
  char* ws = (char*)d_ws;
  float* stats   = (float*)(ws + 0);         // 128 f32 (sums, sumsq)
  float* ss      = (float*)(ws + 1024);      // 128 f32 (scale, shift)
  float* embpart = (float*)(ws + 4096);      // [2][2][1024][32] f32      (512 KB)
  float* h       = (float*)(ws + 528384);    // [8192][64] f32            (2 MB)
  float* QTf     = (float*)(ws + 2625536);   // [16][32][1024] f32        (2 MB)
  u16* KTb       = (u16*)(ws + 4722688);     // [16][32][1024] bf16       (1 MB)
  u16* G         = (u16*)(ws + 5771264);     // [16][1024][1024] bf16     (32 MB)
  u16* Gt        = (u16*)(ws + 39325696);    // transpose                 (32 MB)
  float* out     = (float*)d_out;

  hipMemsetAsync(stats, 0, 512, stream);
  k_h<<<32, 256, 0, stream>>>(hd, W1, b1, h);
  k_stats<<<64, 256, 0, stream>>>(h, stats);
  k_finalize<<<1, 64, 0, stream>>>(stats, gamma, beta, ss);
  k_emb<<<512, 256, 0, stream>>>(embd, embu, WQ, WK, embpart);
  k_dyqk<<<32, 256, 0, stream>>>(h, ss, W2, b2, WQ, WK, embpart, QTf, KTb);
  k_attn<<<512, 256, 0, stream>>>(QTf, KTb, adj0, adj1, G, out);
  k_tr<<<4096, 256, 0, stream>>>(G, Gt);
  k_gemm<<<1024, 256, 0, stream>>>(G, Gt, out);
}

// Round 12
// 403.916 us; speedup vs baseline: 1.5086x; 1.0319x over previous
//
#include <hip/hip_runtime.h>

typedef unsigned short u16;
typedef unsigned int   u32;

typedef __bf16 bf16x8 __attribute__((ext_vector_type(8)));
typedef float  f32x4  __attribute__((ext_vector_type(4)));
typedef u32    u32x2  __attribute__((ext_vector_type(2)));

__device__ __forceinline__ float bf2f(u16 u) {
  u32 x = ((u32)u) << 16; float f; __builtin_memcpy(&f, &x, 4); return f;
}
__device__ __forceinline__ u16 f2bf(float f) {
  u32 x; __builtin_memcpy(&x, &f, 4);
  x += 0x7fffu + ((x >> 16) & 1u);
  return (u16)(x >> 16);
}
__device__ __forceinline__ void gl2lds16(const void* g, void* l) {
  __builtin_amdgcn_global_load_lds((const __attribute__((address_space(1))) void*)g,
                                   (__attribute__((address_space(3))) void*)l, 16, 0, 0);
}

// ---------------- K1: h = relu(X @ W1 + b1), h:[8192,64] f32 ----------------
__global__ __launch_bounds__(256) void k_h(const float* __restrict__ hd, const float* __restrict__ W1,
                                           const float* __restrict__ b1, float* __restrict__ h)
{
  __shared__ float w1s[12 * 64];
  __shared__ float b1s[64];
  int t = threadIdx.x;
  for (int idx = t; idx < 768; idx += 256) w1s[idx] = W1[idx];
  if (t < 64) b1s[t] = b1[t];
  __syncthreads();
  int i = blockIdx.x * 256 + t;
  int b = i >> 10, n = i & 1023;
  float x[12];
#pragma unroll
  for (int l = 0; l < 12; ++l) x[l] = hd[(b * 12 + l) * 1024 + n];
  float acc[64];
#pragma unroll
  for (int j = 0; j < 64; ++j) acc[j] = b1s[j];
#pragma unroll
  for (int l = 0; l < 12; ++l) {
    float xl = x[l];
#pragma unroll
    for (int j = 0; j < 64; ++j) acc[j] += xl * w1s[l * 64 + j];
  }
  float4* hv = (float4*)(h + (size_t)i * 64);
#pragma unroll
  for (int j4 = 0; j4 < 16; ++j4) {
    float4 v;
    v.x = fmaxf(acc[j4 * 4 + 0], 0.f);
    v.y = fmaxf(acc[j4 * 4 + 1], 0.f);
    v.z = fmaxf(acc[j4 * 4 + 2], 0.f);
    v.w = fmaxf(acc[j4 * 4 + 3], 0.f);
    hv[j4] = v;
  }
}

// ---------------- K2a: column sums/sumsq of h (BN stats) ----------------
__global__ __launch_bounds__(256) void k_stats(const float* __restrict__ h, float* __restrict__ stats)
{
  int t = threadIdx.x;
  size_t base = (size_t)blockIdx.x * 8192;
  float s = 0.f, sq = 0.f;
  for (int it = 0; it < 32; ++it) {
    float v = h[base + it * 256 + t];  // column = t & 63, invariant over it
    s += v; sq += v * v;
  }
  __shared__ float ls[256], lq[256];
  ls[t] = s; lq[t] = sq;
  __syncthreads();
  if (t < 64) {
    float S = ls[t] + ls[t + 64] + ls[t + 128] + ls[t + 192];
    float Q = lq[t] + lq[t + 64] + lq[t + 128] + lq[t + 192];
    atomicAdd(&stats[t], S);
    atomicAdd(&stats[64 + t], Q);
  }
}

// ---------------- K2b: finalize BN scale/shift ----------------
__global__ void k_finalize(const float* __restrict__ stats, const float* __restrict__ gamma,
                           const float* __restrict__ beta, float* __restrict__ ss)
{
  int t = threadIdx.x;  // 64 threads
  float mu = stats[t] * (1.f / 8192.f);
  float var = stats[64 + t] * (1.f / 8192.f) - mu * mu;
  float inv = rsqrtf(var + 1e-5f);
  float sc = gamma[t] * inv;
  ss[t] = sc;
  ss[64 + t] = beta[t] - mu * sc;
}

// ---------------- K0: embedding parts of Q/K: emb @ W[32:48,:] ----------------
// embpart layout [e][qk][n][32]
__global__ __launch_bounds__(256) void k_emb(const float* __restrict__ embd, const float* __restrict__ embu,
                                             const float* __restrict__ WQ, const float* __restrict__ WK,
                                             float* __restrict__ embpart)
{
  int g = blockIdx.x * 256 + threadIdx.x;  // 131072 total
  int o = g & 31, n = (g >> 5) & 1023, qk = (g >> 15) & 1, e = g >> 16;
  const float* emb = e ? embu : embd;
  const float* W = qk ? WK : WQ;
  float acc = 0.f;
#pragma unroll
  for (int d = 0; d < 16; ++d) acc += emb[n * 16 + d] * W[(32 + d) * 32 + o];
  embpart[g] = acc;
}

// ---------------- K3: dy_feat + Q/K; Q stored f32 transposed, K stored bf16 transposed ------
__global__ __launch_bounds__(256) void k_dyqk(const float* __restrict__ h, const float* __restrict__ ss,
                                              const float* __restrict__ W2, const float* __restrict__ b2,
                                              const float* __restrict__ WQ, const float* __restrict__ WK,
                                              const float* __restrict__ embpart,
                                              float* __restrict__ QTf, u16* __restrict__ KTb)
{
  __shared__ float w2s[64 * 32], wqs[32 * 32], wks[32 * 32], b2s[32], scs[64], shs[64];
  int t = threadIdx.x;
  for (int idx = t; idx < 2048; idx += 256) w2s[idx] = W2[idx];
  for (int idx = t; idx < 1024; idx += 256) { wqs[idx] = WQ[idx]; wks[idx] = WK[idx]; }
  if (t < 32) b2s[t] = b2[t];
  if (t < 64) { scs[t] = ss[t]; shs[t] = ss[64 + t]; }
  __syncthreads();
  int i = blockIdx.x * 256 + t;
  int b = i >> 10, n = i & 1023;
  float dy[32];
#pragma unroll
  for (int o = 0; o < 32; ++o) dy[o] = b2s[o];
  for (int j = 0; j < 64; ++j) {
    float hj = h[(size_t)i * 64 + j] * scs[j] + shs[j];
#pragma unroll
    for (int o = 0; o < 32; ++o) dy[o] += hj * w2s[j * 32 + o];
  }
  float tq[32], tk[32];
#pragma unroll
  for (int o = 0; o < 32; ++o) { tq[o] = 0.f; tk[o] = 0.f; }
  for (int j = 0; j < 32; ++j) {
    float d = dy[j];
#pragma unroll
    for (int o = 0; o < 32; ++o) { tq[o] += d * wqs[j * 32 + o]; tk[o] += d * wks[j * 32 + o]; }
  }
#pragma unroll
  for (int e = 0; e < 2; ++e) {
    const float* epQ = embpart + ((size_t)(e * 2 + 0) * 1024 + n) * 32;
    const float* epK = embpart + ((size_t)(e * 2 + 1) * 1024 + n) * 32;
    size_t qb = ((size_t)(e * 8 + b) * 32) * 1024 + n;
#pragma unroll
    for (int o = 0; o < 32; ++o) {
      QTf[qb + (size_t)o * 1024] = tq[o] + epQ[o];          // coalesced over n
      KTb[qb + (size_t)o * 1024] = f2bf(tk[o] + epK[o]);
    }
  }
}

// ---------------- K5: fused logits/exp/mask/row-normalize + order-1 output + G ----------------
// softmax denominator cancels against row normalization; logits are O(1) so no max-subtraction.
__global__ __launch_bounds__(256) void k_attn(const float* __restrict__ QTf, const u16* __restrict__ KTb,
                                              const float* __restrict__ adj0, const float* __restrict__ adj1,
                                              u16* __restrict__ G, float* __restrict__ out)
{
  int blk = (blockIdx.x & 7) * 64 + (blockIdx.x >> 3);  // T1 chunked swizzle, 512 wgs
  int rg = blk & 31, b = (blk >> 5) & 7, e = blk >> 8;
  int t = threadIdx.x;
  int eb = e * 8 + b;
  int wv = t >> 6, lane = t & 63;
  const float* adj = e ? adj1 : adj0;
  const u16* Kp = KTb + ((size_t)eb << 15);      // [h][m] bf16 slab, 64 KB, L2-resident
  const float* Qp = QTf + ((size_t)eb << 15);
  u16* Gp = G + ((size_t)eb << 20);
  float* o1 = out + (((size_t)(2 * e) * 8 + b) << 21);
  const float sc = 0.17677669529663687f;  // 1/sqrt(32)
#pragma unroll
  for (int grp = 0; grp < 2; ++grp) {
    int r0 = rg * 32 + wv * 8 + grp * 4;  // 4 rows per group
    float accA[4][8], accB[4][8];
#pragma unroll
    for (int r = 0; r < 4; ++r)
#pragma unroll
      for (int k = 0; k < 8; ++k) { accA[r][k] = 0.f; accB[r][k] = 0.f; }
    for (int hh = 0; hh < 32; ++hh) {
      float4 qv = *(const float4*)(Qp + hh * 1024 + r0);
      uint4 ka = *(const uint4*)(Kp + hh * 1024 + lane * 8);        // m = lane*8 .. +7
      uint4 kb = *(const uint4*)(Kp + hh * 1024 + 512 + lane * 8);  // m = 512 + lane*8 .. +7
      float kf[8] = {bf2f((u16)ka.x), bf2f((u16)(ka.x >> 16)), bf2f((u16)ka.y), bf2f((u16)(ka.y >> 16)),
                     bf2f((u16)ka.z), bf2f((u16)(ka.z >> 16)), bf2f((u16)ka.w), bf2f((u16)(ka.w >> 16))};
      float kg[8] = {bf2f((u16)kb.x), bf2f((u16)(kb.x >> 16)), bf2f((u16)kb.y), bf2f((u16)(kb.y >> 16)),
                     bf2f((u16)kb.z), bf2f((u16)(kb.z >> 16)), bf2f((u16)kb.w), bf2f((u16)(kb.w >> 16))};
#pragma unroll
      for (int k = 0; k < 8; ++k) {
        accA[0][k] += qv.x * kf[k]; accA[1][k] += qv.y * kf[k];
        accA[2][k] += qv.z * kf[k]; accA[3][k] += qv.w * kf[k];
        accB[0][k] += qv.x * kg[k]; accB[1][k] += qv.y * kg[k];
        accB[2][k] += qv.z * kg[k]; accB[3][k] += qv.w * kg[k];
      }
    }
#pragma unroll
    for (int r = 0; r < 4; ++r) {
      int gr = r0 + r;
      const float* arow = adj + ((size_t)gr << 10);
      int mA = lane * 8, mB = 512 + lane * 8;
      float4 a0 = *(const float4*)(arow + mA);
      float4 a1 = *(const float4*)(arow + mA + 4);
      float4 c0 = *(const float4*)(arow + mB);
      float4 c1 = *(const float4*)(arow + mB + 4);
      float af[8] = {a0.x, a0.y, a0.z, a0.w, a1.x, a1.y, a1.z, a1.w};
      float bfv[8] = {c0.x, c0.y, c0.z, c0.w, c1.x, c1.y, c1.z, c1.w};
      float ta[8], tb[8];
      float p = 0.f;
#pragma unroll
      for (int k = 0; k < 8; ++k) { ta[k] = (af[k] + 1e-7f) * __expf(accA[r][k] * sc); p += ta[k]; }
#pragma unroll
      for (int k = 0; k < 8; ++k) { tb[k] = (bfv[k] + 1e-7f) * __expf(accB[r][k] * sc); p += tb[k]; }
#pragma unroll
      for (int off = 32; off > 0; off >>= 1) p += __shfl_xor(p, off);
      float inv = 1.f / p;
      if (!__builtin_isfinite(inv)) inv = 0.f;
      float ga[8], gb[8];
#pragma unroll
      for (int k = 0; k < 8; ++k) { ga[k] = ta[k] * inv; gb[k] = tb[k] * inv; }
      // G row with diagonal intact (needed for g@g), bf16
      uint4 pa, pb;
      pa.x = f2bf(ga[0]) | ((u32)f2bf(ga[1]) << 16);  pa.y = f2bf(ga[2]) | ((u32)f2bf(ga[3]) << 16);
      pa.z = f2bf(ga[4]) | ((u32)f2bf(ga[5]) << 16);  pa.w = f2bf(ga[6]) | ((u32)f2bf(ga[7]) << 16);
      pb.x = f2bf(gb[0]) | ((u32)f2bf(gb[1]) << 16);  pb.y = f2bf(gb[2]) | ((u32)f2bf(gb[3]) << 16);
      pb.z = f2bf(gb[4]) | ((u32)f2bf(gb[5]) << 16);  pb.w = f2bf(gb[6]) | ((u32)f2bf(gb[7]) << 16);
      *(uint4*)(Gp + ((size_t)gr << 10) + mA) = pa;
      *(uint4*)(Gp + ((size_t)gr << 10) + mB) = pb;
      // order-1 output: zero diag, row duplicated, f32
#pragma unroll
      for (int k = 0; k < 8; ++k) {
        if (mA + k == gr) ga[k] = 0.f;
        if (mB + k == gr) gb[k] = 0.f;
      }
      size_t ob = (size_t)gr << 11;
      float4 fa0 = {ga[0], ga[1], ga[2], ga[3]}, fa1 = {ga[4], ga[5], ga[6], ga[7]};
      float4 fb0 = {gb[0], gb[1], gb[2], gb[3]}, fb1 = {gb[4], gb[5], gb[6], gb[7]};
      *(float4*)(o1 + ob + mA) = fa0;         *(float4*)(o1 + ob + mA + 4) = fa1;
      *(float4*)(o1 + ob + mB) = fb0;         *(float4*)(o1 + ob + mB + 4) = fb1;
      *(float4*)(o1 + ob + 1024 + mA) = fa0;  *(float4*)(o1 + ob + 1024 + mA + 4) = fa1;
      *(float4*)(o1 + ob + 1024 + mB) = fb0;  *(float4*)(o1 + ob + 1024 + mB + 4) = fb1;
    }
  }
}

// ---------------- K6: batched C = G@G via bf16 MFMA; B read straight from G via tr_b16 -------
// k_tr/Gt deleted. B-tile (G[k0..k0+32][tj*128..+128]) is staged with linear global_load_lds
// into a [s=n/16][u=perm(k/4)][j=k&3][n&15] subtiled LDS layout via pre-swizzled per-lane
// sources (m173/#21 pattern); ds_read_b64_tr_b16 then delivers the MFMA B-fragment
// (lane gets column n&15, two reads cover k=quad*8..+8; unit perm [0,2,4,6,1,3,5,7]).
__global__ __launch_bounds__(256) void k_gemm(const u16* __restrict__ G, float* __restrict__ out)
{
  __shared__ __align__(16) u16 As[2][128 * 32];
  __shared__ __align__(16) u16 Bs[2][4096];   // 8 KB per buffer, subtiled for tr_b16
  int bid = (blockIdx.x & 7) * 128 + (blockIdx.x >> 3);  // T1 chunked swizzle, 1024 wgs
  int mat = bid >> 6, tile = bid & 63, ti = tile >> 3, tj = tile & 7;
  size_t mo = (size_t)mat << 20;
  const u16* A = G + mo;
  int t = threadIdx.x;
  int w = t >> 6, lane = t & 63;
  int quad = lane >> 4, l16 = lane & 15;
  int wr = (w & 1) * 64, wc = (w >> 1) * 64;
  int s_n0 = wc >> 4;  // n-subtile base for this wave's column block
  f32x4 acc[4][4];
#pragma unroll
  for (int i = 0; i < 4; ++i)
#pragma unroll
    for (int j = 0; j < 4; ++j) acc[i][j] = f32x4{0.f, 0.f, 0.f, 0.f};

  // per-lane pre-swizzled B source (k0-independent part): chunk c = sbase+lane
  const u16* bsrc[2];
#pragma unroll
  for (int it = 0; it < 2; ++it) {
    int c = (it * 4 + w) * 64 + lane;
    int u = (c >> 3) & 7, j = (c >> 1) & 3;
    int klocal = ((u & 3) << 3) + ((u >> 2) << 2) + j;  // unit perm: u->k-subtile [0,2,4,6,1,3,5,7]
    bsrc[it] = A + (size_t)klocal * 1024 + tj * 128 + ((c >> 6) & 7) * 16 + (c & 1) * 8;
  }

#define STAGE(buf, kk)                                                                  \
  {                                                                                     \
    _Pragma("unroll")                                                                   \
    for (int it = 0; it < 2; ++it) {                                                    \
      int sbase = (it * 4 + w) * 64;                                                    \
      int sA = sbase + lane;                                                            \
      int r = sA >> 2, cc = sA & 3;                                                     \
      gl2lds16(A + (size_t)(ti * 128 + r) * 1024 + (kk) + cc * 8,                       \
               (u16*)As[buf] + (size_t)sbase * 8);                                      \
      gl2lds16(bsrc[it] + (size_t)(kk) * 1024,                                          \
               (u16*)Bs[buf] + (size_t)sbase * 8);                                      \
    }                                                                                   \
  }

  STAGE(0, 0);
  __syncthreads();
  int cur = 0;
  for (int k0 = 0; k0 < 1024; k0 += 32) {
    if (k0 + 32 < 1024) STAGE(cur ^ 1, k0 + 32);   // prefetch overlaps compute below
    // A fragments: compiler ds_read_b128 from row-major slab (unchanged)
    bf16x8 af[4];
#pragma unroll
    for (int mt = 0; mt < 4; ++mt)
      af[mt] = *(const bf16x8*)&As[cur][(wr + mt * 16 + l16) * 32 + quad * 8];
    // B fragments: hardware transpose reads
    u32 bb = (u32)(size_t)(const __attribute__((address_space(3))) u16*)&Bs[cur][0];
    u32 laddr = bb + (u32)lane * 8;
    u32x2 r1[4], r2[4];
#pragma unroll
    for (int nt = 0; nt < 4; ++nt) {
      u32 a = laddr + (u32)(s_n0 + nt) * 1024;
      asm volatile("ds_read_b64_tr_b16 %0, %1" : "=v"(r1[nt]) : "v"(a));
      asm volatile("ds_read_b64_tr_b16 %0, %1 offset:512" : "=v"(r2[nt]) : "v"(a));
    }
    asm volatile("s_waitcnt lgkmcnt(0)" ::: "memory");   // tr-read data landed
    __builtin_amdgcn_sched_barrier(0);                   // rule #18: no consumer hoists above
    bf16x8 bfr[4];
#pragma unroll
    for (int nt = 0; nt < 4; ++nt) {
      u32 tmp[4] = {r1[nt].x, r1[nt].y, r2[nt].x, r2[nt].y};  // k = 8q+0..3, 8q+4..7
      __builtin_memcpy(&bfr[nt], tmp, 16);
    }
#pragma unroll
    for (int mt = 0; mt < 4; ++mt)
#pragma unroll
      for (int nt = 0; nt < 4; ++nt)
        acc[mt][nt] = __builtin_amdgcn_mfma_f32_16x16x32_bf16(af[mt], bfr[nt], acc[mt][nt], 0, 0, 0);
    __syncthreads();  // drains vmcnt (prefetch done) + lgkmcnt for all waves
    cur ^= 1;
  }
#undef STAGE
  int e = mat >> 3, bb2 = mat & 7;
  float* o2 = out + (((size_t)(2 * e + 1) * 8 + bb2) << 21);
#pragma unroll
  for (int mt = 0; mt < 4; ++mt)
#pragma unroll
    for (int r = 0; r < 4; ++r) {
      int gr = ti * 128 + wr + mt * 16 + quad * 4 + r;
      size_t rb = (size_t)gr << 11;
#pragma unroll
      for (int nt = 0; nt < 4; ++nt) {
        int gc = tj * 128 + wc + nt * 16 + l16;
        float v = (gr == gc) ? 0.f : acc[mt][nt][r];
        o2[rb + gc] = v;
        o2[rb + 1024 + gc] = v;
      }
    }
}

extern "C" void kernel_launch(void* const* d_in, const int* in_sizes, int n_in,
                              void* d_out, int out_size, void* d_ws, size_t ws_size,
                              hipStream_t stream) {
  const float* hd    = (const float*)d_in[0];
  const float* embd  = (const float*)d_in[1];
  const float* embu  = (const float*)d_in[2];
  const float* adj0  = (const float*)d_in[3];
  const float* adj1  = (const float*)d_in[4];
  const float* W1    = (const float*)d_in[5];
  const float* b1    = (const float*)d_in[6];
  const float* gamma = (const float*)d_in[7];
  const float* beta  = (const float*)d_in[8];
  const float* W2    = (const float*)d_in[9];
  const float* b2    = (const float*)d_in[10];
  const float* WQ    = (const float*)d_in[11];
  const float* WK    = (const float*)d_in[12];
  char* ws = (char*)d_ws;
  float* stats   = (float*)(ws + 0);         // 128 f32 (sums, sumsq)
  float* ss      = (float*)(ws + 1024);      // 128 f32 (scale, shift)
  float* embpart = (float*)(ws + 4096);      // [2][2][1024][32] f32      (512 KB)
  float* h       = (float*)(ws + 528384);    // [8192][64] f32            (2 MB)
  float* QTf     = (float*)(ws + 2625536);   // [16][32][1024] f32        (2 MB)
  u16* KTb       = (u16*)(ws + 4722688);     // [16][32][1024] bf16       (1 MB)
  u16* G         = (u16*)(ws + 5771264);     // [16][1024][1024] bf16     (32 MB)
  float* out     = (float*)d_out;

  hipMemsetAsync(stats, 0, 512, stream);
  k_h<<<32, 256, 0, stream>>>(hd, W1, b1, h);
  k_stats<<<64, 256, 0, stream>>>(h, stats);
  k_finalize<<<1, 64, 0, stream>>>(stats, gamma, beta, ss);
  k_emb<<<512, 256, 0, stream>>>(embd, embu, WQ, WK, embpart);
  k_dyqk<<<32, 256, 0, stream>>>(h, ss, W2, b2, WQ, WK, embpart, QTf, KTb);
  k_attn<<<512, 256, 0, stream>>>(QTf, KTb, adj0, adj1, G, out);
  k_gemm<<<1024, 256, 0, stream>>>(G, out);
}